// Round 11
// baseline (199.366 us; speedup 1.0000x reference)
//
#include <hip/hip_runtime.h>

typedef unsigned short u16;
typedef __attribute__((ext_vector_type(8))) short bf16x8;
typedef __attribute__((ext_vector_type(4))) float f32x4;
typedef __attribute__((ext_vector_type(16))) float f32x16;
typedef unsigned int u32;
typedef __attribute__((ext_vector_type(2))) u32 u32x2;
typedef __attribute__((ext_vector_type(4))) u32 u32x4;

__device__ __forceinline__ u16 f2bf(float f) {
  u32 x = __float_as_uint(f);
  return (u16)((x + 0x7fffu + ((x >> 16) & 1u)) >> 16);
}
__device__ __forceinline__ u32 cvt_pk_bf16(float lo, float hi) {
  u32 r;
  asm("v_cvt_pk_bf16_f32 %0, %1, %2" : "=v"(r) : "v"(lo), "v"(hi));
  return r;
}
// async global->LDS, 16B per lane; dest is wave-uniform base + lane*16
__device__ __forceinline__ void gload16(const u16* g, u16* l) {
  __builtin_amdgcn_global_load_lds(
      (const __attribute__((address_space(1))) u32*)g,
      (__attribute__((address_space(3))) u32*)l, 16, 0, 0);
}

// ===================== merged prep (1 kernel) =====================
#define NZ_Y   2097152
#define N_XP   2228224
#define N_W2B  16384
#define N_HBP  262144
#define N_RS   16384
#define EW_BLOCKS   18048
#define WT1_BLOCKS  (52 * 17)
#define W1T_BLOCKS  (5 * 14 * 4)
#define W2T_BLOCKS  (16 * 13 * 4)
#define PREP_BLOCKS (EW_BLOCKS + WT1_BLOCKS + W1T_BLOCKS + W2T_BLOCKS)

__global__ __launch_bounds__(256) void k_prep(
    const float* __restrict__ x, const float* __restrict__ rs,
    const float* __restrict__ Wq, const float* __restrict__ bq,
    const float* __restrict__ Wk, const float* __restrict__ bk,
    const float* __restrict__ Wv, const float* __restrict__ bv,
    const float* __restrict__ Win, const float* __restrict__ bin,
    const float* __restrict__ W1, const float* __restrict__ b1,
    const float* __restrict__ W2, const float* __restrict__ b2,
    u16* __restrict__ xp, u16* __restrict__ Wt1, u16* __restrict__ W1t,
    u16* __restrict__ W2t, u16* __restrict__ hbuf, float* __restrict__ out) {
  __shared__ float T[32][33];
  int b = blockIdx.x;
  if (b < EW_BLOCKS) {
    int i = b * 256 + threadIdx.x;
    if (i < NZ_Y) { out[i] = 0.f; return; }          // zero y (mlp2 atomic-accumulates)
    i -= NZ_Y;
    if (i < N_XP) {
      int m = i / 544, k = i % 544;
      float v = (k < 512) ? x[m * 512 + k] : (k == 512 ? 1.f : 0.f);
      xp[i] = f2bf(v);
      return;
    }
    i -= N_XP;
    if (i < N_W2B) {
      int c = i >> 5, kk = i & 31;
      W2t[(size_t)c * 1696 + 1664 + kk] = (kk < 4) ? f2bf(b2[kk * 512 + c]) : (u16)0;
      return;
    }
    i -= N_W2B;
    if (i < N_HBP) {
      int mr = i >> 4, d = i & 15;
      hbuf[mr * 160 + 144 + d] = f2bf(d == 0 ? 1.f : 0.f);
      return;
    }
    i -= N_HBP;
    out[2097152 + i] = rs[i];
    return;
  }
  b -= EW_BLOCKS;
  const int tx = threadIdx.x & 31, ty0 = threadIdx.x >> 5;
  if (b < WT1_BLOCKS) {
    const int c0 = (b % 52) * 32, k0 = (b / 52) * 32;
    const float* W; const float* bias; int ldc, cbase, cmax;
    if (c0 < 512)       { W = Wq;  bias = bq;  ldc = 512; cbase = 0;    cmax = 512; }
    else if (c0 < 1024) { W = Wk;  bias = bk;  ldc = 512; cbase = 512;  cmax = 512; }
    else if (c0 < 1536) { W = Wv;  bias = bv;  ldc = 512; cbase = 1024; cmax = 512; }
    else                { W = Win; bias = bin; ldc = 64;  cbase = 1536; cmax = 64;  }
    const int cc = c0 - cbase + tx;
#pragma unroll
    for (int rr = 0; rr < 4; ++rr) {
      int k = k0 + ty0 + rr * 8;
      float v = 0.f;
      if (cc < cmax) {
        if (k < 512)       v = W[k * ldc + cc];
        else if (k == 512) v = bias[cc];
      }
      T[ty0 + rr * 8][tx] = v;
    }
    __syncthreads();
    const float scale = (c0 < 512) ? 0.25f : 1.f;   // SCALE = HD^-0.5
#pragma unroll
    for (int rr = 0; rr < 4; ++rr) {
      int c = c0 + ty0 + rr * 8, k = k0 + tx;
      Wt1[(size_t)c * 544 + k] = f2bf(T[tx][ty0 + rr * 8] * scale);
    }
    return;
  }
  b -= WT1_BLOCKS;
  if (b < W1T_BLOCKS) {
    const int d0 = (b % 5) * 32, e0 = ((b / 5) % 14) * 32, r = b / 70;
#pragma unroll
    for (int rr = 0; rr < 4; ++rr) {
      int d = d0 + ty0 + rr * 8, e = e0 + tx;
      float v = 0.f;
      if (e < 405) {
        if (d < 144)       v = W1[(r * 144 + d) * 405 + e];
        else if (d == 144) v = b1[r * 405 + e];
      }
      T[ty0 + rr * 8][tx] = v;
    }
    __syncthreads();
#pragma unroll
    for (int rr = 0; rr < 4; ++rr) {
      int e = e0 + ty0 + rr * 8, d = d0 + tx;
      W1t[(size_t)r * 71680 + e * 160 + d] = f2bf(T[tx][ty0 + rr * 8]);
    }
    return;
  }
  b -= W1T_BLOCKS;
  {
    const int c0 = (b % 16) * 32, e0 = ((b / 16) % 13) * 32, r = b / 208;
#pragma unroll
    for (int rr = 0; rr < 4; ++rr) {
      int e = e0 + ty0 + rr * 8, c = c0 + tx;
      T[ty0 + rr * 8][tx] = (e < 405) ? W2[((size_t)r * 405 + e) * 512 + c] : 0.f;
    }
    __syncthreads();
#pragma unroll
    for (int rr = 0; rr < 4; ++rr) {
      int c = c0 + ty0 + rr * 8, e = e0 + tx;
      W2t[(size_t)c * 1696 + r * 416 + e] = f2bf(T[tx][ty0 + rr * 8]);
    }
  }
}

// ========= MFMA core A: 128x64 tile, global_load_lds dbuf, swizzled linear LDS =========
__device__ __forceinline__ void mfma_block128(
    const u16* __restrict__ Ag, int ldA,
    const u16* __restrict__ Bg, int ldB,
    int nstep, f32x4 (&acc)[4][2]) {
  __shared__ u16 Al[2][128][32];
  __shared__ u16 Bl[2][64][32];
  const int tid = threadIdx.x, lane = tid & 63, w = tid >> 6;
  const int wr = (tid >> 7) & 1, wc = (tid >> 6) & 1;
  const int lrow = lane & 15, q = lane >> 4;
  const int pk = (q ^ ((lrow >> 1) & 3)) * 8;     // physical elem offset for all frag reads
  const int srow = lane >> 2, sseg = lane & 3;
  const int sw = (sseg ^ ((srow >> 1) & 3)) * 8;
  const u16* As0 = Ag + (size_t)(w * 16 + srow) * ldA + sw;
  const u16* As1 = Ag + (size_t)((w + 4) * 16 + srow) * ldA + sw;
  const u16* Bs0 = Bg + (size_t)(w * 16 + srow) * ldB + sw;

#define STAGE128(buf, s) do { const int kk0 = (s) * 32;            \
    gload16(As0 + kk0, &Al[buf][w * 16][0]);                       \
    gload16(As1 + kk0, &Al[buf][(w + 4) * 16][0]);                 \
    gload16(Bs0 + kk0, &Bl[buf][w * 16][0]); } while (0)

  STAGE128(0, 0);
  __syncthreads();
  int cur = 0;
  for (int s = 0; s < nstep; ++s) {
    const bool more = (s + 1 < nstep);
    if (more) STAGE128(cur ^ 1, s + 1);
    bf16x8 af[4], bf[2];
#pragma unroll
    for (int fm = 0; fm < 4; ++fm)
      af[fm] = *(const bf16x8*)&Al[cur][wr * 64 + fm * 16 + lrow][pk];
#pragma unroll
    for (int fn = 0; fn < 2; ++fn)
      bf[fn] = *(const bf16x8*)&Bl[cur][wc * 32 + fn * 16 + lrow][pk];
#pragma unroll
    for (int fm = 0; fm < 4; ++fm)
#pragma unroll
      for (int fn = 0; fn < 2; ++fn)
        acc[fm][fn] = __builtin_amdgcn_mfma_f32_16x16x32_bf16(
            af[fm], bf[fn], acc[fm][fn], 0, 0, 0);
    if (more) { __syncthreads(); cur ^= 1; }
  }
#undef STAGE128
}

// ========= MFMA core B: 128x128 tile, global_load_lds dbuf, swizzled linear LDS =========
__device__ __forceinline__ void mfma_block_sq(
    const u16* __restrict__ Ag, int ldA,
    const u16* __restrict__ Bg, int ldB,
    int nstep, f32x4 (&acc)[4][4]) {
  __shared__ u16 Al[2][128][32];
  __shared__ u16 Bl[2][128][32];
  const int tid = threadIdx.x, lane = tid & 63, w = tid >> 6;
  const int wr = w >> 1, wc = w & 1;
  const int lrow = lane & 15, q = lane >> 4;
  const int pk = (q ^ ((lrow >> 1) & 3)) * 8;
  const int srow = lane >> 2, sseg = lane & 3;
  const int sw = (sseg ^ ((srow >> 1) & 3)) * 8;
  const u16* As0 = Ag + (size_t)(w * 16 + srow) * ldA + sw;
  const u16* As1 = Ag + (size_t)((w + 4) * 16 + srow) * ldA + sw;
  const u16* Bs0 = Bg + (size_t)(w * 16 + srow) * ldB + sw;
  const u16* Bs1 = Bg + (size_t)((w + 4) * 16 + srow) * ldB + sw;

#define STAGESQ(buf, s) do { const int kk0 = (s) * 32;             \
    gload16(As0 + kk0, &Al[buf][w * 16][0]);                       \
    gload16(As1 + kk0, &Al[buf][(w + 4) * 16][0]);                 \
    gload16(Bs0 + kk0, &Bl[buf][w * 16][0]);                       \
    gload16(Bs1 + kk0, &Bl[buf][(w + 4) * 16][0]); } while (0)

  STAGESQ(0, 0);
  __syncthreads();
  int cur = 0;
  for (int s = 0; s < nstep; ++s) {
    const bool more = (s + 1 < nstep);
    if (more) STAGESQ(cur ^ 1, s + 1);
    bf16x8 af[4], bf[4];
#pragma unroll
    for (int fm = 0; fm < 4; ++fm)
      af[fm] = *(const bf16x8*)&Al[cur][wr * 64 + fm * 16 + lrow][pk];
#pragma unroll
    for (int fn = 0; fn < 4; ++fn)
      bf[fn] = *(const bf16x8*)&Bl[cur][wc * 64 + fn * 16 + lrow][pk];
#pragma unroll
    for (int fm = 0; fm < 4; ++fm)
#pragma unroll
      for (int fn = 0; fn < 4; ++fn)
        acc[fm][fn] = __builtin_amdgcn_mfma_f32_16x16x32_bf16(
            af[fm], bf[fn], acc[fm][fn], 0, 0, 0);
    if (more) { __syncthreads(); cur ^= 1; }
  }
#undef STAGESQ
}

// ===================== GEMM1 (128x128): xp @ Wt1^T -> qb/kb/vt/hbuf =====================
// V-tiles (n0 in [1024,1536)) write vt via LDS transpose -> coalesced 16B stores.
__global__ __launch_bounds__(256) void k_gemm1(
    const u16* __restrict__ xp, const u16* __restrict__ Wt1,
    u16* __restrict__ qb, u16* __restrict__ kb, u16* __restrict__ vt,
    u16* __restrict__ hbuf) {
  __shared__ u16 vbuf[128][130];
  f32x4 acc[4][4];
#pragma unroll
  for (int a = 0; a < 4; ++a)
#pragma unroll
    for (int b = 0; b < 4; ++b) acc[a][b] = (f32x4){0.f, 0.f, 0.f, 0.f};
  const int n0 = blockIdx.x * 128, m0 = blockIdx.y * 128;
  mfma_block_sq(xp + (size_t)m0 * 544, 544, Wt1 + (size_t)n0 * 544, 544, 17, acc);

  const int lane = threadIdx.x & 63;
  const int w = threadIdx.x >> 6, wr = w >> 1, wc = w & 1;
  const int rr = (lane >> 4) * 4, cl = lane & 15;
  const bool isV = (n0 >= 1024) && (n0 < 1536);
  if (isV) {
    // acc -> LDS (row = local m, col = local c), then coalesced transpose-out
#pragma unroll
    for (int fm = 0; fm < 4; ++fm)
#pragma unroll
      for (int i = 0; i < 4; ++i)
#pragma unroll
        for (int fn = 0; fn < 4; ++fn)
          vbuf[wr * 64 + fm * 16 + rr + i][wc * 64 + fn * 16 + cl] =
              f2bf(acc[fm][fn][i]);
    __syncthreads();
    const int bb = m0 >> 9, t0 = m0 & 511;
#pragma unroll
    for (int it = 0; it < 8; ++it) {
      int idx = it * 256 + threadIdx.x;
      int gd = idx >> 4;          // local col 0..127
      int seg = idx & 15;         // 8 t-values each
      int q2 = (n0 - 1024) + gd;  // 0..511
      u16 tmp[8];
#pragma unroll
      for (int j = 0; j < 8; ++j) tmp[j] = vbuf[seg * 8 + j][gd];
      u32x4 pk4;
      pk4.x = (u32)tmp[0] | ((u32)tmp[1] << 16);
      pk4.y = (u32)tmp[2] | ((u32)tmp[3] << 16);
      pk4.z = (u32)tmp[4] | ((u32)tmp[5] << 16);
      pk4.w = (u32)tmp[6] | ((u32)tmp[7] << 16);
      size_t base = ((size_t)((bb << 5) + (q2 >> 4)) * 16 + (q2 & 15)) * 512
                    + t0 + seg * 8;
      *(u32x4*)(vt + base) = pk4;
    }
    return;
  }
#pragma unroll
  for (int fm = 0; fm < 4; ++fm) {
#pragma unroll
    for (int i = 0; i < 4; ++i) {
      int m = m0 + wr * 64 + fm * 16 + rr + i;
      int bb = m >> 9, t = m & 511;
#pragma unroll
      for (int fn = 0; fn < 4; ++fn) {
        int c = n0 + wc * 64 + fn * 16 + cl;
        if (c >= 1600) continue;
        float v = acc[fm][fn][i];
        if (c < 512) {
          qb[((size_t)(((bb << 5) + (c >> 4)) * 512 + t)) * 16 + (c & 15)] = f2bf(v);
        } else if (c < 1024) {
          int q2 = c - 512;
          kb[((size_t)(((bb << 5) + (q2 >> 4)) * 512 + t)) * 16 + (q2 & 15)] = f2bf(v);
        } else {
          int q2 = c - 1536;
          hbuf[(m * 4 + (q2 >> 4)) * 160 + 128 + (q2 & 15)] = f2bf(v);
        }
      }
    }
  }
}

// ========= attention: 512 blocks x 4 waves (2 blocks/CU), 2 streams/wave =========
__global__ __launch_bounds__(256) void k_attn(
    const u16* __restrict__ qb, const u16* __restrict__ kb,
    const u16* __restrict__ vt, u16* __restrict__ hbuf) {
  __shared__ u16 P_lds[4][2][32][40];
  const int bg = blockIdx.x >> 1, half = blockIdx.x & 1, tid = threadIdx.x;
  const int w = tid >> 6, lane = tid & 63;
  const int l31 = lane & 31, hi = lane >> 5;
  const int cl = lane & 15, hq = lane >> 4;
  const int bb = bg >> 5, g = bg & 31, ru = g >> 3, hh = g & 7;
  const u16* qg = qb + (size_t)bg * 512 * 16;
  const u16* kg = kb + (size_t)bg * 512 * 16;
  const u16* vg = vt + (size_t)bg * 16 * 512;
  const f32x16 z16 = {0.f, 0.f, 0.f, 0.f, 0.f, 0.f, 0.f, 0.f,
                      0.f, 0.f, 0.f, 0.f, 0.f, 0.f, 0.f, 0.f};

  const int qbase = half * 256 + w * 64;
  bf16x8 qf[2];
  qf[0] = *(const bf16x8*)(qg + (size_t)(qbase + l31) * 16 + hi * 8);
  qf[1] = *(const bf16x8*)(qg + (size_t)(qbase + 32 + l31) * 16 + hi * 8);
  f32x4 oacc[2][2];
#pragma unroll
  for (int s = 0; s < 2; ++s)
#pragma unroll
    for (int rf = 0; rf < 2; ++rf) oacc[s][rf] = (f32x4){0.f, 0.f, 0.f, 0.f};
  float lsum[2] = {0.f, 0.f};
  const int dmask_e = (l31 & 3) | ((l31 >> 3) << 2);
  const bool dmask_on = (((l31 >> 2) & 1) == hi);
  const int dtile = half * 8 + w * 2;     // q-tile index of stream 0

  for (int c = 0; c < 16; ++c) {
    bf16x8 kf = *(const bf16x8*)(kg + (size_t)(c * 32 + l31) * 16 + hi * 8);
    bf16x8 vb = *(const bf16x8*)(vg + (size_t)cl * 512 + c * 32 + hq * 8);
    f32x16 st[2];
    st[0] = __builtin_amdgcn_mfma_f32_32x32x16_bf16(kf, qf[0], z16, 0, 0, 0);
    st[1] = __builtin_amdgcn_mfma_f32_32x32x16_bf16(kf, qf[1], z16, 0, 0, 0);
#pragma unroll
    for (int s = 0; s < 2; ++s) {
      float e[16];
#pragma unroll
      for (int t = 0; t < 16; ++t) e[t] = __expf(st[s][t]);
      if (c == dtile + s) {
        if (dmask_on) e[dmask_e] = 0.f;
      }
      float t0 = (e[0] + e[1]) + (e[2] + e[3]);
      float t1 = (e[4] + e[5]) + (e[6] + e[7]);
      float t2 = (e[8] + e[9]) + (e[10] + e[11]);
      float t3 = (e[12] + e[13]) + (e[14] + e[15]);
      lsum[s] += (t0 + t1) + (t2 + t3);
#pragma unroll
      for (int gg = 0; gg < 4; ++gg) {
        u32x2 pkv;
        pkv.x = cvt_pk_bf16(e[4 * gg + 0], e[4 * gg + 1]);
        pkv.y = cvt_pk_bf16(e[4 * gg + 2], e[4 * gg + 3]);
        *(u32x2*)&P_lds[w][s][l31][8 * gg + 4 * hi] = pkv;
      }
      bf16x8 pa0 = *(const bf16x8*)&P_lds[w][s][cl][hq * 8];
      bf16x8 pa1 = *(const bf16x8*)&P_lds[w][s][16 + cl][hq * 8];
      oacc[s][0] = __builtin_amdgcn_mfma_f32_16x16x32_bf16(pa0, vb, oacc[s][0], 0, 0, 0);
      oacc[s][1] = __builtin_amdgcn_mfma_f32_16x16x32_bf16(pa1, vb, oacc[s][1], 0, 0, 0);
    }
  }
#pragma unroll
  for (int s = 0; s < 2; ++s) {
    float lfull = lsum[s] + __shfl_xor(lsum[s], 32);
#pragma unroll
    for (int rf = 0; rf < 2; ++rf)
#pragma unroll
      for (int j = 0; j < 4; ++j) {
        int qrow = rf * 16 + hq * 4 + j;
        float denom = __shfl(lfull, qrow);
        int t = qbase + s * 32 + qrow;
        hbuf[((size_t)((bb * 512 + t) * 4 + ru)) * 160 + hh * 16 + cl] =
            f2bf(oacc[s][rf][j] / denom);
      }
  }
}

// ===================== MLP1: hbuf @ W1t -> h1 (relu, *rs, bf16) =====================
__global__ __launch_bounds__(256) void k_mlp1(
    const u16* __restrict__ hbuf, const u16* __restrict__ W1t,
    const float* __restrict__ rsb, u16* __restrict__ h1) {
  f32x4 acc[4][2];
#pragma unroll
  for (int a = 0; a < 4; ++a)
#pragma unroll
    for (int b = 0; b < 2; ++b) acc[a][b] = (f32x4){0.f, 0.f, 0.f, 0.f};
  const int n0 = blockIdx.x * 64, m0 = blockIdx.y * 128, r = blockIdx.z;
  mfma_block128(hbuf + (size_t)m0 * 640 + r * 160, 640,
                W1t + (size_t)(r * 448 + n0) * 160, 160, 5, acc);

  const int lane = threadIdx.x & 63;
  const int wr = (threadIdx.x >> 7) & 1, wc = (threadIdx.x >> 6) & 1;
  const int rr = (lane >> 4) * 4, cl = lane & 15;
#pragma unroll
  for (int fm = 0; fm < 4; ++fm) {
#pragma unroll
    for (int i = 0; i < 4; ++i) {
      int m = m0 + wr * 64 + fm * 16 + rr + i;
      float rsv = rsb[m * 4 + r];
#pragma unroll
      for (int fn = 0; fn < 2; ++fn) {
        int e = n0 + wc * 32 + fn * 16 + cl;
        if (e < 416)
          h1[(size_t)m * 1696 + r * 416 + e] = f2bf(rsv * fmaxf(acc[fm][fn][i], 0.f));
      }
    }
  }
  if (blockIdx.x == 6 && threadIdx.x < 128) {
    int m = m0 + threadIdx.x;
    h1[(size_t)m * 1696 + 1664 + r] = f2bf(rsb[m * 4 + r]);
    if (r == 0)
      for (int z = 1668; z < 1696; ++z) h1[(size_t)m * 1696 + z] = 0;
  }
}

// ============ MLP2: h1 @ W2t^T -> y, split-K=4, atomic f32 accumulate ============
__global__ __launch_bounds__(256) void k_mlp2(
    const u16* __restrict__ h1, const u16* __restrict__ W2t,
    float* __restrict__ yout) {
  f32x4 acc[4][2];
#pragma unroll
  for (int a = 0; a < 4; ++a)
#pragma unroll
    for (int b = 0; b < 2; ++b) acc[a][b] = (f32x4){0.f, 0.f, 0.f, 0.f};
  const int n0 = blockIdx.x * 64, m0 = blockIdx.y * 128;
  const int kz = blockIdx.z;                     // 0..3
  const int kb0 = kz ? (448 + (kz - 1) * 416) : 0;   // 0,448,864,1280
  const int ns  = kz ? 13 : 14;                  // 14+13+13+13 = 53 steps (K=1696)
  mfma_block128(h1 + (size_t)m0 * 1696 + kb0, 1696,
                W2t + (size_t)n0 * 1696 + kb0, 1696, ns, acc);

  const int lane = threadIdx.x & 63;
  const int wr = (threadIdx.x >> 7) & 1, wc = (threadIdx.x >> 6) & 1;
  const int rr = (lane >> 4) * 4, cl = lane & 15;
#pragma unroll
  for (int fm = 0; fm < 4; ++fm) {
#pragma unroll
    for (int i = 0; i < 4; ++i) {
      int m = m0 + wr * 64 + fm * 16 + rr + i;
#pragma unroll
      for (int fn = 0; fn < 2; ++fn) {
        int c = n0 + wc * 32 + fn * 16 + cl;
        unsafeAtomicAdd(&yout[(size_t)m * 512 + c], acc[fm][fn][i]);
      }
    }
  }
}

extern "C" void kernel_launch(void* const* d_in, const int* in_sizes, int n_in,
                              void* d_out, int out_size, void* d_ws, size_t ws_size,
                              hipStream_t stream) {
  const float* x    = (const float*)d_in[0];
  const float* rs   = (const float*)d_in[1];
  const float* Wq   = (const float*)d_in[2];
  const float* bq   = (const float*)d_in[3];
  const float* Wk   = (const float*)d_in[4];
  const float* bk   = (const float*)d_in[5];
  const float* Wv   = (const float*)d_in[6];
  const float* bv   = (const float*)d_in[7];
  const float* Win  = (const float*)d_in[8];
  const float* bin  = (const float*)d_in[9];
  const float* W1   = (const float*)d_in[10];
  const float* b1   = (const float*)d_in[11];
  const float* W2   = (const float*)d_in[12];
  const float* b2   = (const float*)d_in[13];
  float* out = (float*)d_out;

  // ws layout (~27.7 MB), all bf16:
  u16* xp   = (u16*)d_ws;             // 2,228,224   [4096][544]
  u16* Wt1  = xp + 2228224;           //   905,216   [1664][544] (rows>=1600 zero)
  u16* W1t  = Wt1 + 905216;           //   286,720   [4][448][160]
  u16* W2t  = W1t + 286720;           //   868,352   [512][1696]
  u16* hbuf = W2t + 868352;           // 2,621,440   [4096][4][160]
  u16* qb   = hbuf + 2621440;         // 2,097,152
  u16* kb   = qb + 2097152;           // 2,097,152
  u16* vt   = kb + 2097152;           // 2,097,152
  u16* h1   = qb;                     // 6,946,816 (aliases qb/kb/vt + tail; dead after attn)

  k_prep<<<PREP_BLOCKS, 256, 0, stream>>>(x, rs, Wq, bq, Wk, bk, Wv, bv, Win, bin,
                                          W1, b1, W2, b2, xp, Wt1, W1t, W2t, hbuf, out);
  k_gemm1<<<dim3(13, 32), 256, 0, stream>>>(xp, Wt1, qb, kb, vt, hbuf);
  k_attn<<<512, 256, 0, stream>>>(qb, kb, vt, hbuf);
  k_mlp1<<<dim3(7, 32, 4), 256, 0, stream>>>(hbuf, W1t, rs, h1);
  k_mlp2<<<dim3(8, 32, 4), 256, 0, stream>>>(h1, W2t, out);
}

// Round 12
// 193.989 us; speedup vs baseline: 1.0277x; 1.0277x over previous
//
#include <hip/hip_runtime.h>

typedef unsigned short u16;
typedef __attribute__((ext_vector_type(8))) short bf16x8;
typedef __attribute__((ext_vector_type(4))) float f32x4;
typedef __attribute__((ext_vector_type(16))) float f32x16;
typedef unsigned int u32;
typedef __attribute__((ext_vector_type(2))) u32 u32x2;

__device__ __forceinline__ u16 f2bf(float f) {
  u32 x = __float_as_uint(f);
  return (u16)((x + 0x7fffu + ((x >> 16) & 1u)) >> 16);
}
__device__ __forceinline__ u32 cvt_pk_bf16(float lo, float hi) {
  u32 r;
  asm("v_cvt_pk_bf16_f32 %0, %1, %2" : "=v"(r) : "v"(lo), "v"(hi));
  return r;
}
// async global->LDS, 16B per lane; dest is wave-uniform base + lane*16
__device__ __forceinline__ void gload16(const u16* g, u16* l) {
  __builtin_amdgcn_global_load_lds(
      (const __attribute__((address_space(1))) u32*)g,
      (__attribute__((address_space(3))) u32*)l, 16, 0, 0);
}
// XCD-chunked swizzle: dispatch id -> logical id so each XCD gets a contiguous chunk
__device__ __forceinline__ int xcd_swz(int bid, int cpx) {
  return (bid & 7) * cpx + (bid >> 3);
}

// ===================== merged prep (1 kernel) =====================
#define NZ_Y   2097152
#define N_XP   2228224
#define N_W2B  16384
#define N_HBP  262144
#define N_RS   16384
#define EW_BLOCKS   18048
#define WT1_BLOCKS  (52 * 17)
#define W1T_BLOCKS  (5 * 14 * 4)
#define W2T_BLOCKS  (16 * 13 * 4)
#define PREP_BLOCKS (EW_BLOCKS + WT1_BLOCKS + W1T_BLOCKS + W2T_BLOCKS)

__global__ __launch_bounds__(256) void k_prep(
    const float* __restrict__ x, const float* __restrict__ rs,
    const float* __restrict__ Wq, const float* __restrict__ bq,
    const float* __restrict__ Wk, const float* __restrict__ bk,
    const float* __restrict__ Wv, const float* __restrict__ bv,
    const float* __restrict__ Win, const float* __restrict__ bin,
    const float* __restrict__ W1, const float* __restrict__ b1,
    const float* __restrict__ W2, const float* __restrict__ b2,
    u16* __restrict__ xp, u16* __restrict__ Wt1, u16* __restrict__ W1t,
    u16* __restrict__ W2t, u16* __restrict__ hbuf, float* __restrict__ out) {
  __shared__ float T[32][33];
  int b = blockIdx.x;
  if (b < EW_BLOCKS) {
    int i = b * 256 + threadIdx.x;
    if (i < NZ_Y) { out[i] = 0.f; return; }          // zero y (mlp2 atomic-accumulates)
    i -= NZ_Y;
    if (i < N_XP) {
      int m = i / 544, k = i % 544;
      float v = (k < 512) ? x[m * 512 + k] : (k == 512 ? 1.f : 0.f);
      xp[i] = f2bf(v);
      return;
    }
    i -= N_XP;
    if (i < N_W2B) {
      int c = i >> 5, kk = i & 31;
      W2t[(size_t)c * 1696 + 1664 + kk] = (kk < 4) ? f2bf(b2[kk * 512 + c]) : (u16)0;
      return;
    }
    i -= N_W2B;
    if (i < N_HBP) {
      int mr = i >> 4, d = i & 15;
      hbuf[mr * 160 + 144 + d] = f2bf(d == 0 ? 1.f : 0.f);
      return;
    }
    i -= N_HBP;
    out[2097152 + i] = rs[i];
    return;
  }
  b -= EW_BLOCKS;
  const int tx = threadIdx.x & 31, ty0 = threadIdx.x >> 5;
  if (b < WT1_BLOCKS) {
    const int c0 = (b % 52) * 32, k0 = (b / 52) * 32;
    const float* W; const float* bias; int ldc, cbase, cmax;
    if (c0 < 512)       { W = Wq;  bias = bq;  ldc = 512; cbase = 0;    cmax = 512; }
    else if (c0 < 1024) { W = Wk;  bias = bk;  ldc = 512; cbase = 512;  cmax = 512; }
    else if (c0 < 1536) { W = Wv;  bias = bv;  ldc = 512; cbase = 1024; cmax = 512; }
    else                { W = Win; bias = bin; ldc = 64;  cbase = 1536; cmax = 64;  }
    const int cc = c0 - cbase + tx;
#pragma unroll
    for (int rr = 0; rr < 4; ++rr) {
      int k = k0 + ty0 + rr * 8;
      float v = 0.f;
      if (cc < cmax) {
        if (k < 512)       v = W[k * ldc + cc];
        else if (k == 512) v = bias[cc];
      }
      T[ty0 + rr * 8][tx] = v;
    }
    __syncthreads();
    const float scale = (c0 < 512) ? 0.25f : 1.f;   // SCALE = HD^-0.5
#pragma unroll
    for (int rr = 0; rr < 4; ++rr) {
      int c = c0 + ty0 + rr * 8, k = k0 + tx;
      Wt1[(size_t)c * 544 + k] = f2bf(T[tx][ty0 + rr * 8] * scale);
    }
    return;
  }
  b -= WT1_BLOCKS;
  if (b < W1T_BLOCKS) {
    const int d0 = (b % 5) * 32, e0 = ((b / 5) % 14) * 32, r = b / 70;
#pragma unroll
    for (int rr = 0; rr < 4; ++rr) {
      int d = d0 + ty0 + rr * 8, e = e0 + tx;
      float v = 0.f;
      if (e < 405) {
        if (d < 144)       v = W1[(r * 144 + d) * 405 + e];
        else if (d == 144) v = b1[r * 405 + e];
      }
      T[ty0 + rr * 8][tx] = v;
    }
    __syncthreads();
#pragma unroll
    for (int rr = 0; rr < 4; ++rr) {
      int e = e0 + ty0 + rr * 8, d = d0 + tx;
      W1t[(size_t)r * 71680 + e * 160 + d] = f2bf(T[tx][ty0 + rr * 8]);
    }
    return;
  }
  b -= W1T_BLOCKS;
  {
    const int c0 = (b % 16) * 32, e0 = ((b / 16) % 13) * 32, r = b / 208;
#pragma unroll
    for (int rr = 0; rr < 4; ++rr) {
      int e = e0 + ty0 + rr * 8, c = c0 + tx;
      T[ty0 + rr * 8][tx] = (e < 405) ? W2[((size_t)r * 405 + e) * 512 + c] : 0.f;
    }
    __syncthreads();
#pragma unroll
    for (int rr = 0; rr < 4; ++rr) {
      int c = c0 + ty0 + rr * 8, e = e0 + tx;
      W2t[(size_t)c * 1696 + r * 416 + e] = f2bf(T[tx][ty0 + rr * 8]);
    }
  }
}

// ========= MFMA core A: 128x64 tile, global_load_lds dbuf, swizzled linear LDS =========
__device__ __forceinline__ void mfma_block128(
    const u16* __restrict__ Ag, int ldA,
    const u16* __restrict__ Bg, int ldB,
    int nstep, f32x4 (&acc)[4][2]) {
  __shared__ u16 Al[2][128][32];
  __shared__ u16 Bl[2][64][32];
  const int tid = threadIdx.x, lane = tid & 63, w = tid >> 6;
  const int wr = (tid >> 7) & 1, wc = (tid >> 6) & 1;
  const int lrow = lane & 15, q = lane >> 4;
  const int pk = (q ^ ((lrow >> 1) & 3)) * 8;     // physical elem offset for all frag reads
  const int srow = lane >> 2, sseg = lane & 3;
  const int sw = (sseg ^ ((srow >> 1) & 3)) * 8;
  const u16* As0 = Ag + (size_t)(w * 16 + srow) * ldA + sw;
  const u16* As1 = Ag + (size_t)((w + 4) * 16 + srow) * ldA + sw;
  const u16* Bs0 = Bg + (size_t)(w * 16 + srow) * ldB + sw;

#define STAGE128(buf, s) do { const int kk0 = (s) * 32;            \
    gload16(As0 + kk0, &Al[buf][w * 16][0]);                       \
    gload16(As1 + kk0, &Al[buf][(w + 4) * 16][0]);                 \
    gload16(Bs0 + kk0, &Bl[buf][w * 16][0]); } while (0)

  STAGE128(0, 0);
  __syncthreads();
  int cur = 0;
  for (int s = 0; s < nstep; ++s) {
    const bool more = (s + 1 < nstep);
    if (more) STAGE128(cur ^ 1, s + 1);
    bf16x8 af[4], bf[2];
#pragma unroll
    for (int fm = 0; fm < 4; ++fm)
      af[fm] = *(const bf16x8*)&Al[cur][wr * 64 + fm * 16 + lrow][pk];
#pragma unroll
    for (int fn = 0; fn < 2; ++fn)
      bf[fn] = *(const bf16x8*)&Bl[cur][wc * 32 + fn * 16 + lrow][pk];
#pragma unroll
    for (int fm = 0; fm < 4; ++fm)
#pragma unroll
      for (int fn = 0; fn < 2; ++fn)
        acc[fm][fn] = __builtin_amdgcn_mfma_f32_16x16x32_bf16(
            af[fm], bf[fn], acc[fm][fn], 0, 0, 0);
    if (more) { __syncthreads(); cur ^= 1; }
  }
#undef STAGE128
}

// ========= MFMA core B: 128x128 tile, global_load_lds dbuf, swizzled linear LDS =========
__device__ __forceinline__ void mfma_block_sq(
    const u16* __restrict__ Ag, int ldA,
    const u16* __restrict__ Bg, int ldB,
    int nstep, f32x4 (&acc)[4][4]) {
  __shared__ u16 Al[2][128][32];
  __shared__ u16 Bl[2][128][32];
  const int tid = threadIdx.x, lane = tid & 63, w = tid >> 6;
  const int wr = w >> 1, wc = w & 1;
  const int lrow = lane & 15, q = lane >> 4;
  const int pk = (q ^ ((lrow >> 1) & 3)) * 8;
  const int srow = lane >> 2, sseg = lane & 3;
  const int sw = (sseg ^ ((srow >> 1) & 3)) * 8;
  const u16* As0 = Ag + (size_t)(w * 16 + srow) * ldA + sw;
  const u16* As1 = Ag + (size_t)((w + 4) * 16 + srow) * ldA + sw;
  const u16* Bs0 = Bg + (size_t)(w * 16 + srow) * ldB + sw;
  const u16* Bs1 = Bg + (size_t)((w + 4) * 16 + srow) * ldB + sw;

#define STAGESQ(buf, s) do { const int kk0 = (s) * 32;             \
    gload16(As0 + kk0, &Al[buf][w * 16][0]);                       \
    gload16(As1 + kk0, &Al[buf][(w + 4) * 16][0]);                 \
    gload16(Bs0 + kk0, &Bl[buf][w * 16][0]);                       \
    gload16(Bs1 + kk0, &Bl[buf][(w + 4) * 16][0]); } while (0)

  STAGESQ(0, 0);
  __syncthreads();
  int cur = 0;
  for (int s = 0; s < nstep; ++s) {
    const bool more = (s + 1 < nstep);
    if (more) STAGESQ(cur ^ 1, s + 1);
    bf16x8 af[4], bf[4];
#pragma unroll
    for (int fm = 0; fm < 4; ++fm)
      af[fm] = *(const bf16x8*)&Al[cur][wr * 64 + fm * 16 + lrow][pk];
#pragma unroll
    for (int fn = 0; fn < 4; ++fn)
      bf[fn] = *(const bf16x8*)&Bl[cur][wc * 64 + fn * 16 + lrow][pk];
#pragma unroll
    for (int fm = 0; fm < 4; ++fm)
#pragma unroll
      for (int fn = 0; fn < 4; ++fn)
        acc[fm][fn] = __builtin_amdgcn_mfma_f32_16x16x32_bf16(
            af[fm], bf[fn], acc[fm][fn], 0, 0, 0);
    if (more) { __syncthreads(); cur ^= 1; }
  }
#undef STAGESQ
}

// ====== GEMM1 (128x128): xp @ Wt1^T -> qb/kb/vt/hbuf. Flat grid 416, XCD swizzle ======
// logical lbid = m0t*13 + n0t : chunk of 52 = 4 m0-panels x all 13 n -> xp L2-resident/XCD
__global__ __launch_bounds__(256) void k_gemm1(
    const u16* __restrict__ xp, const u16* __restrict__ Wt1,
    u16* __restrict__ qb, u16* __restrict__ kb, u16* __restrict__ vt,
    u16* __restrict__ hbuf) {
  f32x4 acc[4][4];
#pragma unroll
  for (int a = 0; a < 4; ++a)
#pragma unroll
    for (int b = 0; b < 4; ++b) acc[a][b] = (f32x4){0.f, 0.f, 0.f, 0.f};
  const int lbid = xcd_swz(blockIdx.x, 52);
  const int n0 = (lbid % 13) * 128, m0 = (lbid / 13) * 128;
  mfma_block_sq(xp + (size_t)m0 * 544, 544, Wt1 + (size_t)n0 * 544, 544, 17, acc);

  const int lane = threadIdx.x & 63;
  const int w = threadIdx.x >> 6, wr = w >> 1, wc = w & 1;
  const int rr = (lane >> 4) * 4, cl = lane & 15;
#pragma unroll
  for (int fm = 0; fm < 4; ++fm) {
#pragma unroll
    for (int i = 0; i < 4; ++i) {
      int m = m0 + wr * 64 + fm * 16 + rr + i;
      int bb = m >> 9, t = m & 511;
#pragma unroll
      for (int fn = 0; fn < 4; ++fn) {
        int c = n0 + wc * 64 + fn * 16 + cl;
        if (c >= 1600) continue;
        float v = acc[fm][fn][i];
        if (c < 512) {
          qb[((size_t)(((bb << 5) + (c >> 4)) * 512 + t)) * 16 + (c & 15)] = f2bf(v);
        } else if (c < 1024) {
          int q2 = c - 512;
          kb[((size_t)(((bb << 5) + (q2 >> 4)) * 512 + t)) * 16 + (q2 & 15)] = f2bf(v);
        } else if (c < 1536) {
          int q2 = c - 1024;
          vt[((size_t)(((bb << 5) + (q2 >> 4)) * 16 + (q2 & 15))) * 512 + t] = f2bf(v);
        } else {
          int q2 = c - 1536;
          hbuf[(m * 4 + (q2 >> 4)) * 160 + 128 + (q2 & 15)] = f2bf(v);
        }
      }
    }
  }
}

// ========= attention: 512 blocks x 4 waves, XCD swizzle keeps bg-pairs on one XCD =========
__global__ __launch_bounds__(256) void k_attn(
    const u16* __restrict__ qb, const u16* __restrict__ kb,
    const u16* __restrict__ vt, u16* __restrict__ hbuf) {
  __shared__ u16 P_lds[4][2][32][40];
  const int lbid = xcd_swz(blockIdx.x, 64);
  const int bg = lbid >> 1, half = lbid & 1, tid = threadIdx.x;
  const int w = tid >> 6, lane = tid & 63;
  const int l31 = lane & 31, hi = lane >> 5;
  const int cl = lane & 15, hq = lane >> 4;
  const int bb = bg >> 5, g = bg & 31, ru = g >> 3, hh = g & 7;
  const u16* qg = qb + (size_t)bg * 512 * 16;
  const u16* kg = kb + (size_t)bg * 512 * 16;
  const u16* vg = vt + (size_t)bg * 16 * 512;
  const f32x16 z16 = {0.f, 0.f, 0.f, 0.f, 0.f, 0.f, 0.f, 0.f,
                      0.f, 0.f, 0.f, 0.f, 0.f, 0.f, 0.f, 0.f};

  const int qbase = half * 256 + w * 64;
  bf16x8 qf[2];
  qf[0] = *(const bf16x8*)(qg + (size_t)(qbase + l31) * 16 + hi * 8);
  qf[1] = *(const bf16x8*)(qg + (size_t)(qbase + 32 + l31) * 16 + hi * 8);
  f32x4 oacc[2][2];
#pragma unroll
  for (int s = 0; s < 2; ++s)
#pragma unroll
    for (int rf = 0; rf < 2; ++rf) oacc[s][rf] = (f32x4){0.f, 0.f, 0.f, 0.f};
  float lsum[2] = {0.f, 0.f};
  const int dmask_e = (l31 & 3) | ((l31 >> 3) << 2);
  const bool dmask_on = (((l31 >> 2) & 1) == hi);
  const int dtile = half * 8 + w * 2;     // q-tile index of stream 0

  for (int c = 0; c < 16; ++c) {
    bf16x8 kf = *(const bf16x8*)(kg + (size_t)(c * 32 + l31) * 16 + hi * 8);
    bf16x8 vb = *(const bf16x8*)(vg + (size_t)cl * 512 + c * 32 + hq * 8);
    f32x16 st[2];
    st[0] = __builtin_amdgcn_mfma_f32_32x32x16_bf16(kf, qf[0], z16, 0, 0, 0);
    st[1] = __builtin_amdgcn_mfma_f32_32x32x16_bf16(kf, qf[1], z16, 0, 0, 0);
#pragma unroll
    for (int s = 0; s < 2; ++s) {
      float e[16];
#pragma unroll
      for (int t = 0; t < 16; ++t) e[t] = __expf(st[s][t]);
      if (c == dtile + s) {
        if (dmask_on) e[dmask_e] = 0.f;
      }
      float t0 = (e[0] + e[1]) + (e[2] + e[3]);
      float t1 = (e[4] + e[5]) + (e[6] + e[7]);
      float t2 = (e[8] + e[9]) + (e[10] + e[11]);
      float t3 = (e[12] + e[13]) + (e[14] + e[15]);
      lsum[s] += (t0 + t1) + (t2 + t3);
#pragma unroll
      for (int gg = 0; gg < 4; ++gg) {
        u32x2 pkv;
        pkv.x = cvt_pk_bf16(e[4 * gg + 0], e[4 * gg + 1]);
        pkv.y = cvt_pk_bf16(e[4 * gg + 2], e[4 * gg + 3]);
        *(u32x2*)&P_lds[w][s][l31][8 * gg + 4 * hi] = pkv;
      }
      bf16x8 pa0 = *(const bf16x8*)&P_lds[w][s][cl][hq * 8];
      bf16x8 pa1 = *(const bf16x8*)&P_lds[w][s][16 + cl][hq * 8];
      oacc[s][0] = __builtin_amdgcn_mfma_f32_16x16x32_bf16(pa0, vb, oacc[s][0], 0, 0, 0);
      oacc[s][1] = __builtin_amdgcn_mfma_f32_16x16x32_bf16(pa1, vb, oacc[s][1], 0, 0, 0);
    }
  }
#pragma unroll
  for (int s = 0; s < 2; ++s) {
    float lfull = lsum[s] + __shfl_xor(lsum[s], 32);
#pragma unroll
    for (int rf = 0; rf < 2; ++rf)
#pragma unroll
      for (int j = 0; j < 4; ++j) {
        int qrow = rf * 16 + hq * 4 + j;
        float denom = __shfl(lfull, qrow);
        int t = qbase + s * 32 + qrow;
        hbuf[((size_t)((bb * 512 + t) * 4 + ru)) * 160 + hh * 16 + cl] =
            f2bf(oacc[s][rf][j] / denom);
      }
  }
}

// ====== MLP1: hbuf @ W1t -> h1 (relu, *rs). Flat grid 896, XCD swizzle ======
// logical lbid = m0t*28 + r*7 + n0t : chunk of 112 = 4 m0 x all (r,n)
__global__ __launch_bounds__(256) void k_mlp1(
    const u16* __restrict__ hbuf, const u16* __restrict__ W1t,
    const float* __restrict__ rsb, u16* __restrict__ h1) {
  f32x4 acc[4][2];
#pragma unroll
  for (int a = 0; a < 4; ++a)
#pragma unroll
    for (int b = 0; b < 2; ++b) acc[a][b] = (f32x4){0.f, 0.f, 0.f, 0.f};
  const int lbid = xcd_swz(blockIdx.x, 112);
  const int m0 = (lbid / 28) * 128;
  const int rest = lbid % 28;
  const int r = rest / 7, n0t = rest % 7;
  const int n0 = n0t * 64;
  mfma_block128(hbuf + (size_t)m0 * 640 + r * 160, 640,
                W1t + (size_t)(r * 448 + n0) * 160, 160, 5, acc);

  const int lane = threadIdx.x & 63;
  const int wr = (threadIdx.x >> 7) & 1, wc = (threadIdx.x >> 6) & 1;
  const int rr = (lane >> 4) * 4, cl = lane & 15;
#pragma unroll
  for (int fm = 0; fm < 4; ++fm) {
#pragma unroll
    for (int i = 0; i < 4; ++i) {
      int m = m0 + wr * 64 + fm * 16 + rr + i;
      float rsv = rsb[m * 4 + r];
#pragma unroll
      for (int fn = 0; fn < 2; ++fn) {
        int e = n0 + wc * 32 + fn * 16 + cl;
        if (e < 416)
          h1[(size_t)m * 1696 + r * 416 + e] = f2bf(rsv * fmaxf(acc[fm][fn][i], 0.f));
      }
    }
  }
  if (n0t == 6 && threadIdx.x < 128) {
    int m = m0 + threadIdx.x;
    h1[(size_t)m * 1696 + 1664 + r] = f2bf(rsb[m * 4 + r]);
    if (r == 0)
      for (int z = 1668; z < 1696; ++z) h1[(size_t)m * 1696 + z] = 0;
  }
}

// ====== MLP2: h1 @ W2t^T -> y, split-K=4 atomics. Flat grid 1024, XCD swizzle ======
// logical lbid = m0t*32 + kz*8 + n0t : chunk of 128 = 4 m0-panels x all (kz,n)
// -> h1 panels (1.7MB) + W2t (1.7MB) resident per XCD-L2
__global__ __launch_bounds__(256) void k_mlp2(
    const u16* __restrict__ h1, const u16* __restrict__ W2t,
    float* __restrict__ yout) {
  f32x4 acc[4][2];
#pragma unroll
  for (int a = 0; a < 4; ++a)
#pragma unroll
    for (int b = 0; b < 2; ++b) acc[a][b] = (f32x4){0.f, 0.f, 0.f, 0.f};
  const int lbid = xcd_swz(blockIdx.x, 128);
  const int m0 = (lbid / 32) * 128;
  const int rest = lbid % 32;
  const int kz = rest >> 3;
  const int n0 = (rest & 7) * 64;
  const int kb0 = kz ? (448 + (kz - 1) * 416) : 0;   // 0,448,864,1280
  const int ns  = kz ? 13 : 14;                      // 14+13+13+13 = 53 steps
  mfma_block128(h1 + (size_t)m0 * 1696 + kb0, 1696,
                W2t + (size_t)n0 * 1696 + kb0, 1696, ns, acc);

  const int lane = threadIdx.x & 63;
  const int wr = (threadIdx.x >> 7) & 1, wc = (threadIdx.x >> 6) & 1;
  const int rr = (lane >> 4) * 4, cl = lane & 15;
#pragma unroll
  for (int fm = 0; fm < 4; ++fm) {
#pragma unroll
    for (int i = 0; i < 4; ++i) {
      int m = m0 + wr * 64 + fm * 16 + rr + i;
#pragma unroll
      for (int fn = 0; fn < 2; ++fn) {
        int c = n0 + wc * 32 + fn * 16 + cl;
        unsafeAtomicAdd(&yout[(size_t)m * 512 + c], acc[fm][fn][i]);
      }
    }
  }
}

extern "C" void kernel_launch(void* const* d_in, const int* in_sizes, int n_in,
                              void* d_out, int out_size, void* d_ws, size_t ws_size,
                              hipStream_t stream) {
  const float* x    = (const float*)d_in[0];
  const float* rs   = (const float*)d_in[1];
  const float* Wq   = (const float*)d_in[2];
  const float* bq   = (const float*)d_in[3];
  const float* Wk   = (const float*)d_in[4];
  const float* bk   = (const float*)d_in[5];
  const float* Wv   = (const float*)d_in[6];
  const float* bv   = (const float*)d_in[7];
  const float* Win  = (const float*)d_in[8];
  const float* bin  = (const float*)d_in[9];
  const float* W1   = (const float*)d_in[10];
  const float* b1   = (const float*)d_in[11];
  const float* W2   = (const float*)d_in[12];
  const float* b2   = (const float*)d_in[13];
  float* out = (float*)d_out;

  // ws layout (~27.7 MB), all bf16:
  u16* xp   = (u16*)d_ws;             // 2,228,224   [4096][544]
  u16* Wt1  = xp + 2228224;           //   905,216   [1664][544] (rows>=1600 zero)
  u16* W1t  = Wt1 + 905216;           //   286,720   [4][448][160]
  u16* W2t  = W1t + 286720;           //   868,352   [512][1696]
  u16* hbuf = W2t + 868352;           // 2,621,440   [4096][4][160]
  u16* qb   = hbuf + 2621440;         // 2,097,152
  u16* kb   = qb + 2097152;           // 2,097,152
  u16* vt   = kb + 2097152;           // 2,097,152
  u16* h1   = qb;                     // 6,946,816 (aliases qb/kb/vt + tail; dead after attn)

  k_prep<<<PREP_BLOCKS, 256, 0, stream>>>(x, rs, Wq, bq, Wk, bk, Wv, bv, Win, bin,
                                          W1, b1, W2, b2, xp, Wt1, W1t, W2t, hbuf, out);
  k_gemm1<<<416, 256, 0, stream>>>(xp, Wt1, qb, kb, vt, hbuf);
  k_attn<<<512, 256, 0, stream>>>(qb, kb, vt, hbuf);
  k_mlp1<<<896, 256, 0, stream>>>(hbuf, W1t, rs, h1);
  k_mlp2<<<1024, 256, 0, stream>>>(h1, W2t, out);
}

// Round 13
// 182.163 us; speedup vs baseline: 1.0944x; 1.0649x over previous
//
#include <hip/hip_runtime.h>

typedef unsigned short u16;
typedef __attribute__((ext_vector_type(8))) short bf16x8;
typedef __attribute__((ext_vector_type(4))) float f32x4;
typedef __attribute__((ext_vector_type(16))) float f32x16;
typedef unsigned int u32;
typedef __attribute__((ext_vector_type(2))) u32 u32x2;
typedef __attribute__((ext_vector_type(4))) u32 u32x4;

__device__ __forceinline__ u16 f2bf(float f) {
  u32 x = __float_as_uint(f);
  return (u16)((x + 0x7fffu + ((x >> 16) & 1u)) >> 16);
}
__device__ __forceinline__ u32 cvt_pk_bf16(float lo, float hi) {
  u32 r;
  asm("v_cvt_pk_bf16_f32 %0, %1, %2" : "=v"(r) : "v"(lo), "v"(hi));
  return r;
}
// XCD-chunked swizzle: dispatch id -> logical id so each XCD gets a contiguous chunk
__device__ __forceinline__ int xcd_swz(int bid, int cpx) {
  return (bid & 7) * cpx + (bid >> 3);
}

// ===================== merged prep (1 kernel, vectorized EW) =====================
// block ranges: [0,2048) y-zero | [2048,4224) xp | [4224,4288) W2t bias
//               [4288,4544) hbuf pad | [4544,4560) rs passthrough | transposes
#define EW_BLOCKS   4560
#define WT1_BLOCKS  (52 * 17)
#define W1T_BLOCKS  (5 * 14 * 4)
#define W2T_BLOCKS  (16 * 13 * 4)
#define PREP_BLOCKS (EW_BLOCKS + WT1_BLOCKS + W1T_BLOCKS + W2T_BLOCKS)

__global__ __launch_bounds__(256) void k_prep(
    const float* __restrict__ x, const float* __restrict__ rs,
    const float* __restrict__ Wq, const float* __restrict__ bq,
    const float* __restrict__ Wk, const float* __restrict__ bk,
    const float* __restrict__ Wv, const float* __restrict__ bv,
    const float* __restrict__ Win, const float* __restrict__ bin,
    const float* __restrict__ W1, const float* __restrict__ b1,
    const float* __restrict__ W2, const float* __restrict__ b2,
    u16* __restrict__ xp, u16* __restrict__ Wt1, u16* __restrict__ W1t,
    u16* __restrict__ W2t, u16* __restrict__ hbuf, float* __restrict__ out) {
  __shared__ float T[32][33];
  int b = blockIdx.x;
  if (b < 2048) {                       // zero y (mlp2 atomic-accumulates), float4
    ((float4*)out)[b * 256 + threadIdx.x] = make_float4(0.f, 0.f, 0.f, 0.f);
    return;
  }
  if (b < 4224) {                       // xp [4096][544]: x | 1.0 | 0-pad, 4 elems/thread
    int idx = (b - 2048) * 256 + threadIdx.x;      // < 557056
    int m = idx / 136, j = idx % 136;
    u16 o[4];
    if (j < 128) {
      float4 v = ((const float4*)x)[m * 128 + j];
      o[0] = f2bf(v.x); o[1] = f2bf(v.y); o[2] = f2bf(v.z); o[3] = f2bf(v.w);
    } else if (j == 128) { o[0] = 0x3F80; o[1] = o[2] = o[3] = 0; }
    else { o[0] = o[1] = o[2] = o[3] = 0; }
    u32x2 pk;
    pk.x = (u32)o[0] | ((u32)o[1] << 16);
    pk.y = (u32)o[2] | ((u32)o[3] << 16);
    *(u32x2*)(xp + (size_t)m * 544 + j * 4) = pk;
    return;
  }
  if (b < 4288) {                       // W2t bias cols @k=1664..1695
    int i = (b - 4224) * 256 + threadIdx.x;        // < 16384
    int c = i >> 5, kk = i & 31;
    W2t[(size_t)c * 1696 + 1664 + kk] = (kk < 4) ? f2bf(b2[kk * 512 + c]) : (u16)0;
    return;
  }
  if (b < 4544) {                       // hbuf pad cols [144..160): 1.0 @144, zeros
    int i = (b - 4288) * 256 + threadIdx.x;        // < 65536
    int mr = i >> 2, d0 = (i & 3) * 4;
    u32x2 pk;
    pk.x = (d0 == 0) ? 0x3F80u : 0u;
    pk.y = 0u;
    *(u32x2*)(hbuf + (size_t)mr * 160 + 144 + d0) = pk;
    return;
  }
  if (b < EW_BLOCKS) {                  // r_scores passthrough (output 1), float4
    int i = (b - 4544) * 256 + threadIdx.x;        // < 4096
    ((float4*)(out + 2097152))[i] = ((const float4*)rs)[i];
    return;
  }
  b -= EW_BLOCKS;
  const int tx = threadIdx.x & 31, ty0 = threadIdx.x >> 5;
  if (b < WT1_BLOCKS) {
    // Wt1 [1664][544]: [Wq|Wk|Wv|Win]^T, bias row @k=512, q-cols scaled, rows>=1600 zero
    const int c0 = (b % 52) * 32, k0 = (b / 52) * 32;
    const float* W; const float* bias; int ldc, cbase, cmax;
    if (c0 < 512)       { W = Wq;  bias = bq;  ldc = 512; cbase = 0;    cmax = 512; }
    else if (c0 < 1024) { W = Wk;  bias = bk;  ldc = 512; cbase = 512;  cmax = 512; }
    else if (c0 < 1536) { W = Wv;  bias = bv;  ldc = 512; cbase = 1024; cmax = 512; }
    else                { W = Win; bias = bin; ldc = 64;  cbase = 1536; cmax = 64;  }
    const int cc = c0 - cbase + tx;
#pragma unroll
    for (int rr = 0; rr < 4; ++rr) {
      int k = k0 + ty0 + rr * 8;
      float v = 0.f;
      if (cc < cmax) {
        if (k < 512)       v = W[k * ldc + cc];
        else if (k == 512) v = bias[cc];
      }
      T[ty0 + rr * 8][tx] = v;
    }
    __syncthreads();
    const float scale = (c0 < 512) ? 0.25f : 1.f;   // SCALE = HD^-0.5
#pragma unroll
    for (int rr = 0; rr < 4; ++rr) {
      int c = c0 + ty0 + rr * 8, k = k0 + tx;
      Wt1[(size_t)c * 544 + k] = f2bf(T[tx][ty0 + rr * 8] * scale);
    }
    return;
  }
  b -= WT1_BLOCKS;
  if (b < W1T_BLOCKS) {
    // W1t [4][448][160]: W1^T (d<->e), b1 slot @d=144, zero pads
    const int d0 = (b % 5) * 32, e0 = ((b / 5) % 14) * 32, r = b / 70;
#pragma unroll
    for (int rr = 0; rr < 4; ++rr) {
      int d = d0 + ty0 + rr * 8, e = e0 + tx;
      float v = 0.f;
      if (e < 405) {
        if (d < 144)       v = W1[(r * 144 + d) * 405 + e];
        else if (d == 144) v = b1[r * 405 + e];
      }
      T[ty0 + rr * 8][tx] = v;
    }
    __syncthreads();
#pragma unroll
    for (int rr = 0; rr < 4; ++rr) {
      int e = e0 + ty0 + rr * 8, d = d0 + tx;
      W1t[(size_t)r * 71680 + e * 160 + d] = f2bf(T[tx][ty0 + rr * 8]);
    }
    return;
  }
  b -= W1T_BLOCKS;
  {
    // W2t [512][1696]: per-rule W2^T (e<->c), e padded 405->416
    const int c0 = (b % 16) * 32, e0 = ((b / 16) % 13) * 32, r = b / 208;
#pragma unroll
    for (int rr = 0; rr < 4; ++rr) {
      int e = e0 + ty0 + rr * 8, c = c0 + tx;
      T[ty0 + rr * 8][tx] = (e < 405) ? W2[((size_t)r * 405 + e) * 512 + c] : 0.f;
    }
    __syncthreads();
#pragma unroll
    for (int rr = 0; rr < 4; ++rr) {
      int c = c0 + ty0 + rr * 8, e = e0 + tx;
      W2t[(size_t)c * 1696 + r * 416 + e] = f2bf(T[tx][ty0 + rr * 8]);
    }
  }
}

// ===================== MFMA core A: 128x64 tile, dbuf LDS + reg prefetch =====================
__device__ __forceinline__ void mfma_block128(
    const u16* __restrict__ Ag, int ldA,
    const u16* __restrict__ Bg, int ldB,
    int nstep, f32x4 (&acc)[4][2]) {
  __shared__ u16 Al[2][128][40];
  __shared__ u16 Bl[2][64][40];
  const int tid = threadIdx.x, lane = tid & 63;
  const int wr = (tid >> 7) & 1, wc = (tid >> 6) & 1;
  const int lrow = lane & 15, lk = (lane >> 4) * 8;
  const int ar0 = tid >> 2, aseg = (tid & 3) * 8;
  const u16* Ap0 = Ag + (size_t)ar0 * ldA + aseg;
  const u16* Ap1 = Ag + (size_t)(ar0 + 64) * ldA + aseg;
  const u16* Bp  = Bg + (size_t)ar0 * ldB + aseg;

  u32x4 a0 = *(const u32x4*)(Ap0);
  u32x4 a1 = *(const u32x4*)(Ap1);
  u32x4 b0 = *(const u32x4*)(Bp);
  *(u32x4*)&Al[0][ar0][aseg]      = a0;
  *(u32x4*)&Al[0][ar0 + 64][aseg] = a1;
  *(u32x4*)&Bl[0][ar0][aseg]      = b0;
  __syncthreads();
  int cur = 0;
  for (int s = 0; s < nstep; ++s) {
    const bool more = (s + 1 < nstep);
    if (more) {                         // issue next-step loads BEFORE consuming current
      const int k0 = (s + 1) * 32;
      a0 = *(const u32x4*)(Ap0 + k0);
      a1 = *(const u32x4*)(Ap1 + k0);
      b0 = *(const u32x4*)(Bp + k0);
    }
    bf16x8 af[4], bf[2];
#pragma unroll
    for (int fm = 0; fm < 4; ++fm)
      af[fm] = *(const bf16x8*)&Al[cur][wr * 64 + fm * 16 + lrow][lk];
#pragma unroll
    for (int fn = 0; fn < 2; ++fn)
      bf[fn] = *(const bf16x8*)&Bl[cur][wc * 32 + fn * 16 + lrow][lk];
#pragma unroll
    for (int fm = 0; fm < 4; ++fm)
#pragma unroll
      for (int fn = 0; fn < 2; ++fn)
        acc[fm][fn] = __builtin_amdgcn_mfma_f32_16x16x32_bf16(
            af[fm], bf[fn], acc[fm][fn], 0, 0, 0);
    if (more) {
      *(u32x4*)&Al[cur ^ 1][ar0][aseg]      = a0;
      *(u32x4*)&Al[cur ^ 1][ar0 + 64][aseg] = a1;
      *(u32x4*)&Bl[cur ^ 1][ar0][aseg]      = b0;
      __syncthreads();                  // single barrier per k-step
      cur ^= 1;
    }
  }
}

// ===================== MFMA core B: 128x128 tile, dbuf LDS + reg prefetch =====================
__device__ __forceinline__ void mfma_block_sq(
    const u16* __restrict__ Ag, int ldA,
    const u16* __restrict__ Bg, int ldB,
    int nstep, f32x4 (&acc)[4][4]) {
  __shared__ u16 Al[2][128][40];
  __shared__ u16 Bl[2][128][40];
  const int tid = threadIdx.x, lane = tid & 63;
  const int w = tid >> 6, wr = w >> 1, wc = w & 1;
  const int lrow = lane & 15, lk = (lane >> 4) * 8;
  const int r0 = tid >> 2, seg = (tid & 3) * 8;
  const u16* Ap0 = Ag + (size_t)r0 * ldA + seg;
  const u16* Ap1 = Ag + (size_t)(r0 + 64) * ldA + seg;
  const u16* Bp0 = Bg + (size_t)r0 * ldB + seg;
  const u16* Bp1 = Bg + (size_t)(r0 + 64) * ldB + seg;

  u32x4 a0 = *(const u32x4*)(Ap0);
  u32x4 a1 = *(const u32x4*)(Ap1);
  u32x4 b0 = *(const u32x4*)(Bp0);
  u32x4 b1 = *(const u32x4*)(Bp1);
  *(u32x4*)&Al[0][r0][seg]      = a0;
  *(u32x4*)&Al[0][r0 + 64][seg] = a1;
  *(u32x4*)&Bl[0][r0][seg]      = b0;
  *(u32x4*)&Bl[0][r0 + 64][seg] = b1;
  __syncthreads();
  int cur = 0;
  for (int s = 0; s < nstep; ++s) {
    const bool more = (s + 1 < nstep);
    if (more) {
      const int k0 = (s + 1) * 32;
      a0 = *(const u32x4*)(Ap0 + k0);
      a1 = *(const u32x4*)(Ap1 + k0);
      b0 = *(const u32x4*)(Bp0 + k0);
      b1 = *(const u32x4*)(Bp1 + k0);
    }
    bf16x8 af[4], bf[4];
#pragma unroll
    for (int fm = 0; fm < 4; ++fm)
      af[fm] = *(const bf16x8*)&Al[cur][wr * 64 + fm * 16 + lrow][lk];
#pragma unroll
    for (int fn = 0; fn < 4; ++fn)
      bf[fn] = *(const bf16x8*)&Bl[cur][wc * 64 + fn * 16 + lrow][lk];
#pragma unroll
    for (int fm = 0; fm < 4; ++fm)
#pragma unroll
      for (int fn = 0; fn < 4; ++fn)
        acc[fm][fn] = __builtin_amdgcn_mfma_f32_16x16x32_bf16(
            af[fm], bf[fn], acc[fm][fn], 0, 0, 0);
    if (more) {
      *(u32x4*)&Al[cur ^ 1][r0][seg]      = a0;
      *(u32x4*)&Al[cur ^ 1][r0 + 64][seg] = a1;
      *(u32x4*)&Bl[cur ^ 1][r0][seg]      = b0;
      *(u32x4*)&Bl[cur ^ 1][r0 + 64][seg] = b1;
      __syncthreads();
      cur ^= 1;
    }
  }
}

// ===================== GEMM1 (128x128): xp @ Wt1^T -> qb/kb/vt/hbuf =====================
__global__ __launch_bounds__(256) void k_gemm1(
    const u16* __restrict__ xp, const u16* __restrict__ Wt1,
    u16* __restrict__ qb, u16* __restrict__ kb, u16* __restrict__ vt,
    u16* __restrict__ hbuf) {
  f32x4 acc[4][4];
#pragma unroll
  for (int a = 0; a < 4; ++a)
#pragma unroll
    for (int b = 0; b < 4; ++b) acc[a][b] = (f32x4){0.f, 0.f, 0.f, 0.f};
  const int n0 = blockIdx.x * 128, m0 = blockIdx.y * 128;
  mfma_block_sq(xp + (size_t)m0 * 544, 544, Wt1 + (size_t)n0 * 544, 544, 17, acc);

  const int lane = threadIdx.x & 63;
  const int w = threadIdx.x >> 6, wr = w >> 1, wc = w & 1;
  const int rr = (lane >> 4) * 4, cl = lane & 15;
#pragma unroll
  for (int fm = 0; fm < 4; ++fm) {
#pragma unroll
    for (int i = 0; i < 4; ++i) {
      int m = m0 + wr * 64 + fm * 16 + rr + i;
      int bb = m >> 9, t = m & 511;
#pragma unroll
      for (int fn = 0; fn < 4; ++fn) {
        int c = n0 + wc * 64 + fn * 16 + cl;
        if (c >= 1600) continue;
        float v = acc[fm][fn][i];
        if (c < 512) {
          qb[((size_t)(((bb << 5) + (c >> 4)) * 512 + t)) * 16 + (c & 15)] = f2bf(v);
        } else if (c < 1024) {
          int q2 = c - 512;
          kb[((size_t)(((bb << 5) + (q2 >> 4)) * 512 + t)) * 16 + (q2 & 15)] = f2bf(v);
        } else if (c < 1536) {
          int q2 = c - 1024;
          vt[((size_t)(((bb << 5) + (q2 >> 4)) * 16 + (q2 & 15))) * 512 + t] = f2bf(v);
        } else {
          int q2 = c - 1536;
          hbuf[(m * 4 + (q2 >> 4)) * 160 + 128 + (q2 & 15)] = f2bf(v);
        }
      }
    }
  }
}

// ========= attention: 512 blocks x 4 waves (2 blocks/CU), 2 streams/wave =========
__global__ __launch_bounds__(256) void k_attn(
    const u16* __restrict__ qb, const u16* __restrict__ kb,
    const u16* __restrict__ vt, u16* __restrict__ hbuf) {
  __shared__ u16 P_lds[4][2][32][40];
  const int bg = blockIdx.x >> 1, half = blockIdx.x & 1, tid = threadIdx.x;
  const int w = tid >> 6, lane = tid & 63;
  const int l31 = lane & 31, hi = lane >> 5;
  const int cl = lane & 15, hq = lane >> 4;
  const int bb = bg >> 5, g = bg & 31, ru = g >> 3, hh = g & 7;
  const u16* qg = qb + (size_t)bg * 512 * 16;
  const u16* kg = kb + (size_t)bg * 512 * 16;
  const u16* vg = vt + (size_t)bg * 16 * 512;
  const f32x16 z16 = {0.f, 0.f, 0.f, 0.f, 0.f, 0.f, 0.f, 0.f,
                      0.f, 0.f, 0.f, 0.f, 0.f, 0.f, 0.f, 0.f};

  const int qbase = half * 256 + w * 64;
  bf16x8 qf[2];
  qf[0] = *(const bf16x8*)(qg + (size_t)(qbase + l31) * 16 + hi * 8);
  qf[1] = *(const bf16x8*)(qg + (size_t)(qbase + 32 + l31) * 16 + hi * 8);
  f32x4 oacc[2][2];
#pragma unroll
  for (int s = 0; s < 2; ++s)
#pragma unroll
    for (int rf = 0; rf < 2; ++rf) oacc[s][rf] = (f32x4){0.f, 0.f, 0.f, 0.f};
  float lsum[2] = {0.f, 0.f};
  const int dmask_e = (l31 & 3) | ((l31 >> 3) << 2);
  const bool dmask_on = (((l31 >> 2) & 1) == hi);
  const int dtile = half * 8 + w * 2;     // q-tile index of stream 0

  for (int c = 0; c < 16; ++c) {
    bf16x8 kf = *(const bf16x8*)(kg + (size_t)(c * 32 + l31) * 16 + hi * 8);
    bf16x8 vb = *(const bf16x8*)(vg + (size_t)cl * 512 + c * 32 + hq * 8);
    f32x16 st[2];
    st[0] = __builtin_amdgcn_mfma_f32_32x32x16_bf16(kf, qf[0], z16, 0, 0, 0);
    st[1] = __builtin_amdgcn_mfma_f32_32x32x16_bf16(kf, qf[1], z16, 0, 0, 0);
#pragma unroll
    for (int s = 0; s < 2; ++s) {
      float e[16];
#pragma unroll
      for (int t = 0; t < 16; ++t) e[t] = __expf(st[s][t]);
      if (c == dtile + s) {
        if (dmask_on) e[dmask_e] = 0.f;
      }
      float t0 = (e[0] + e[1]) + (e[2] + e[3]);
      float t1 = (e[4] + e[5]) + (e[6] + e[7]);
      float t2 = (e[8] + e[9]) + (e[10] + e[11]);
      float t3 = (e[12] + e[13]) + (e[14] + e[15]);
      lsum[s] += (t0 + t1) + (t2 + t3);
#pragma unroll
      for (int gg = 0; gg < 4; ++gg) {
        u32x2 pkv;
        pkv.x = cvt_pk_bf16(e[4 * gg + 0], e[4 * gg + 1]);
        pkv.y = cvt_pk_bf16(e[4 * gg + 2], e[4 * gg + 3]);
        *(u32x2*)&P_lds[w][s][l31][8 * gg + 4 * hi] = pkv;
      }
      bf16x8 pa0 = *(const bf16x8*)&P_lds[w][s][cl][hq * 8];
      bf16x8 pa1 = *(const bf16x8*)&P_lds[w][s][16 + cl][hq * 8];
      oacc[s][0] = __builtin_amdgcn_mfma_f32_16x16x32_bf16(pa0, vb, oacc[s][0], 0, 0, 0);
      oacc[s][1] = __builtin_amdgcn_mfma_f32_16x16x32_bf16(pa1, vb, oacc[s][1], 0, 0, 0);
    }
  }
#pragma unroll
  for (int s = 0; s < 2; ++s) {
    float lfull = lsum[s] + __shfl_xor(lsum[s], 32);
#pragma unroll
    for (int rf = 0; rf < 2; ++rf)
#pragma unroll
      for (int j = 0; j < 4; ++j) {
        int qrow = rf * 16 + hq * 4 + j;
        float denom = __shfl(lfull, qrow);
        int t = qbase + s * 32 + qrow;
        hbuf[((size_t)((bb * 512 + t) * 4 + ru)) * 160 + hh * 16 + cl] =
            f2bf(oacc[s][rf][j] / denom);
      }
  }
}

// ===================== MLP1: hbuf @ W1t -> h1 (relu, *rs, bf16) =====================
__global__ __launch_bounds__(256) void k_mlp1(
    const u16* __restrict__ hbuf, const u16* __restrict__ W1t,
    const float* __restrict__ rsb, u16* __restrict__ h1) {
  f32x4 acc[4][2];
#pragma unroll
  for (int a = 0; a < 4; ++a)
#pragma unroll
    for (int b = 0; b < 2; ++b) acc[a][b] = (f32x4){0.f, 0.f, 0.f, 0.f};
  const int n0 = blockIdx.x * 64, m0 = blockIdx.y * 128, r = blockIdx.z;
  mfma_block128(hbuf + (size_t)m0 * 640 + r * 160, 640,
                W1t + (size_t)(r * 448 + n0) * 160, 160, 5, acc);

  const int lane = threadIdx.x & 63;
  const int wr = (threadIdx.x >> 7) & 1, wc = (threadIdx.x >> 6) & 1;
  const int rr = (lane >> 4) * 4, cl = lane & 15;
#pragma unroll
  for (int fm = 0; fm < 4; ++fm) {
#pragma unroll
    for (int i = 0; i < 4; ++i) {
      int m = m0 + wr * 64 + fm * 16 + rr + i;
      float rsv = rsb[m * 4 + r];
#pragma unroll
      for (int fn = 0; fn < 2; ++fn) {
        int e = n0 + wc * 32 + fn * 16 + cl;
        if (e < 416)
          h1[(size_t)m * 1696 + r * 416 + e] = f2bf(rsv * fmaxf(acc[fm][fn][i], 0.f));
      }
    }
  }
  if (blockIdx.x == 6 && threadIdx.x < 128) {
    int m = m0 + threadIdx.x;
    h1[(size_t)m * 1696 + 1664 + r] = f2bf(rsb[m * 4 + r]);
    if (r == 0)
      for (int z = 1668; z < 1696; ++z) h1[(size_t)m * 1696 + z] = 0;
  }
}

// ====== MLP2: h1 @ W2t^T -> y, split-K=2 atomics. Flat grid 512, XCD swizzle ======
// logical lbid = m0t*16 + kz*8 + n0t : chunk of 64 = 4 m0-panels x all (kz,n)
// -> h1 panels (1.7MB) + W2t (1.7MB) resident per XCD-L2
__global__ __launch_bounds__(256) void k_mlp2(
    const u16* __restrict__ h1, const u16* __restrict__ W2t,
    float* __restrict__ yout) {
  f32x4 acc[4][2];
#pragma unroll
  for (int a = 0; a < 4; ++a)
#pragma unroll
    for (int b = 0; b < 2; ++b) acc[a][b] = (f32x4){0.f, 0.f, 0.f, 0.f};
  const int lbid = xcd_swz(blockIdx.x, 64);
  const int m0 = (lbid / 16) * 128;
  const int rest = lbid % 16;
  const int kz = rest >> 3;
  const int n0 = (rest & 7) * 64;
  const int kb0 = kz ? 864 : 0;
  const int ns  = kz ? 26 : 27;      // 27+26 = 53 K-steps of 32 (K=1696)
  mfma_block128(h1 + (size_t)m0 * 1696 + kb0, 1696,
                W2t + (size_t)n0 * 1696 + kb0, 1696, ns, acc);

  const int lane = threadIdx.x & 63;
  const int wr = (threadIdx.x >> 7) & 1, wc = (threadIdx.x >> 6) & 1;
  const int rr = (lane >> 4) * 4, cl = lane & 15;
#pragma unroll
  for (int fm = 0; fm < 4; ++fm) {
#pragma unroll
    for (int i = 0; i < 4; ++i) {
      int m = m0 + wr * 64 + fm * 16 + rr + i;
#pragma unroll
      for (int fn = 0; fn < 2; ++fn) {
        int c = n0 + wc * 32 + fn * 16 + cl;
        unsafeAtomicAdd(&yout[(size_t)m * 512 + c], acc[fm][fn][i]);
      }
    }
  }
}

extern "C" void kernel_launch(void* const* d_in, const int* in_sizes, int n_in,
                              void* d_out, int out_size, void* d_ws, size_t ws_size,
                              hipStream_t stream) {
  const float* x    = (const float*)d_in[0];
  const float* rs   = (const float*)d_in[1];
  const float* Wq   = (const float*)d_in[2];
  const float* bq   = (const float*)d_in[3];
  const float* Wk   = (const float*)d_in[4];
  const float* bk   = (const float*)d_in[5];
  const float* Wv   = (const float*)d_in[6];
  const float* bv   = (const float*)d_in[7];
  const float* Win  = (const float*)d_in[8];
  const float* bin  = (const float*)d_in[9];
  const float* W1   = (const float*)d_in[10];
  const float* b1   = (const float*)d_in[11];
  const float* W2   = (const float*)d_in[12];
  const float* b2   = (const float*)d_in[13];
  float* out = (float*)d_out;

  // ws layout (~27.7 MB), all bf16:
  u16* xp   = (u16*)d_ws;             // 2,228,224   [4096][544]
  u16* Wt1  = xp + 2228224;           //   905,216   [1664][544] (rows>=1600 zero)
  u16* W1t  = Wt1 + 905216;           //   286,720   [4][448][160]
  u16* W2t  = W1t + 286720;           //   868,352   [512][1696]
  u16* hbuf = W2t + 868352;           // 2,621,440   [4096][4][160]
  u16* qb   = hbuf + 2621440;         // 2,097,152
  u16* kb   = qb + 2097152;           // 2,097,152
  u16* vt   = kb + 2097152;           // 2,097,152
  u16* h1   = qb;                     // 6,946,816 (aliases qb/kb/vt + tail; dead after attn)

  k_prep<<<PREP_BLOCKS, 256, 0, stream>>>(x, rs, Wq, bq, Wk, bk, Wv, bv, Win, bin,
                                          W1, b1, W2, b2, xp, Wt1, W1t, W2t, hbuf, out);
  k_gemm1<<<dim3(13, 32), 256, 0, stream>>>(xp, Wt1, qb, kb, vt, hbuf);
  k_attn<<<512, 256, 0, stream>>>(qb, kb, vt, hbuf);
  k_mlp1<<<dim3(7, 32, 4), 256, 0, stream>>>(hbuf, W1t, rs, h1);
  k_mlp2<<<512, 256, 0, stream>>>(h1, W2t, out);
}